// Round 6
// baseline (588.758 us; speedup 1.0000x reference)
//
#include <hip/hip_runtime.h>

#define T_SEQ 512
#define U_TAGS 128
#define D_DIM 1024
#define M_ROWS (64 * T_SEQ)  // 32768

// ---------------------------------------------------------------------------
// Kernel 1: partial GEMM over half of K. 512 threads (8 waves), 128x128 tile,
// BK=32, 4x8 micro. Same ascending-k fmaf order per accumulator as the proven
// 586us kernel -> bitwise-identical partials. vs round-0: 16 waves/CU
// (2 blocks/CU) instead of 8, half the barriers.
// ---------------------------------------------------------------------------
__global__ __launch_bounds__(512) void crf_gemm_half(
    const float* __restrict__ A, const float* __restrict__ Bk,
    float* __restrict__ Cpart) {
  __shared__ float As[32][132];  // [k][row] (transposed)
  __shared__ float Bs[32][132];  // [k][col]
  const int tid = threadIdx.x;
  const int row0 = blockIdx.x * 128;
  const int kbase = blockIdx.y * (D_DIM / 2);

  // micro-tile: 16 x 32 thread grid, each 4 rows x 8 cols
  const int tx = tid & 15, ty = tid >> 4;  // ty 0..31

  // staging decomposition (1024 slots each for A and B, 2 per thread)
  const int ar = tid >> 3, aq = tid & 7;   // A slot t: row ar, k-quad aq
  const int bk = tid >> 5, bn = tid & 31;  // B slot t: k bk, col-quad bn

  float acc[4][8] = {};

  float4 a0 = *(const float4*)&A[(size_t)(row0 + ar) * D_DIM + kbase + aq * 4];
  float4 a1 =
      *(const float4*)&A[(size_t)(row0 + ar + 64) * D_DIM + kbase + aq * 4];
  float4 b0 = *(const float4*)&Bk[(size_t)(kbase + bk) * U_TAGS + bn * 4];
  float4 b1 = *(const float4*)&Bk[(size_t)(kbase + bk + 16) * U_TAGS + bn * 4];

  for (int k0 = 0; k0 < D_DIM / 2; k0 += 32) {
    As[aq * 4 + 0][ar] = a0.x; As[aq * 4 + 1][ar] = a0.y;
    As[aq * 4 + 2][ar] = a0.z; As[aq * 4 + 3][ar] = a0.w;
    As[aq * 4 + 0][ar + 64] = a1.x; As[aq * 4 + 1][ar + 64] = a1.y;
    As[aq * 4 + 2][ar + 64] = a1.z; As[aq * 4 + 3][ar + 64] = a1.w;
    *(float4*)&Bs[bk][bn * 4] = b0;
    *(float4*)&Bs[bk + 16][bn * 4] = b1;
    __syncthreads();
    if (k0 + 32 < D_DIM / 2) {
      const int kn = kbase + k0 + 32;
      a0 = *(const float4*)&A[(size_t)(row0 + ar) * D_DIM + kn + aq * 4];
      a1 = *(const float4*)&A[(size_t)(row0 + ar + 64) * D_DIM + kn + aq * 4];
      b0 = *(const float4*)&Bk[(size_t)(kn + bk) * U_TAGS + bn * 4];
      b1 = *(const float4*)&Bk[(size_t)(kn + bk + 16) * U_TAGS + bn * 4];
    }
#pragma unroll
    for (int kk = 0; kk < 32; ++kk) {
      float a[4], b[8];
      *(float4*)&a[0] = *(const float4*)&As[kk][ty * 4];
      *(float4*)&b[0] = *(const float4*)&Bs[kk][tx * 4];
      *(float4*)&b[4] = *(const float4*)&Bs[kk][tx * 4 + 64];
#pragma unroll
      for (int r = 0; r < 4; ++r)
#pragma unroll
        for (int c = 0; c < 8; ++c) acc[r][c] = fmaf(a[r], b[c], acc[r][c]);
    }
    __syncthreads();
  }

  float* Cp = Cpart + (size_t)blockIdx.y * M_ROWS * U_TAGS;
#pragma unroll
  for (int r = 0; r < 4; ++r) {
    const int row = row0 + ty * 4 + r;
    *(float4*)&Cp[(size_t)row * U_TAGS + tx * 4] = *(float4*)&acc[r][0];
    *(float4*)&Cp[(size_t)row * U_TAGS + tx * 4 + 64] = *(float4*)&acc[r][4];
  }
}

// ---------------------------------------------------------------------------
// Fallback single-K GEMM (only if ws too small). Unchanged from 586us kernel.
// ---------------------------------------------------------------------------
__global__ __launch_bounds__(256) void crf_gemm(
    const float* __restrict__ A, const float* __restrict__ Bk,
    const float* __restrict__ bias, const float* __restrict__ lb,
    const float* __restrict__ rb, float* __restrict__ C) {
  __shared__ float As[16][132];
  __shared__ float Bs[16][132];
  const int tid = threadIdx.x;
  const int tx = tid & 15, ty = tid >> 4;
  const int row0 = blockIdx.x * 128;
  const int am = tid >> 2, ak = (tid & 3) << 2;
  const int bk = tid >> 5, bn = (tid & 31) << 2;
  float acc[8][8] = {};
  float4 a0 = *(const float4*)&A[(size_t)(row0 + am) * D_DIM + ak];
  float4 a1 = *(const float4*)&A[(size_t)(row0 + am + 64) * D_DIM + ak];
  float4 b0 = *(const float4*)&Bk[(size_t)bk * U_TAGS + bn];
  float4 b1 = *(const float4*)&Bk[(size_t)(bk + 8) * U_TAGS + bn];
  for (int k0 = 0; k0 < D_DIM; k0 += 16) {
    As[ak + 0][am] = a0.x; As[ak + 1][am] = a0.y;
    As[ak + 2][am] = a0.z; As[ak + 3][am] = a0.w;
    As[ak + 0][am + 64] = a1.x; As[ak + 1][am + 64] = a1.y;
    As[ak + 2][am + 64] = a1.z; As[ak + 3][am + 64] = a1.w;
    *(float4*)&Bs[bk][bn] = b0;
    *(float4*)&Bs[bk + 8][bn] = b1;
    __syncthreads();
    if (k0 + 16 < D_DIM) {
      a0 = *(const float4*)&A[(size_t)(row0 + am) * D_DIM + k0 + 16 + ak];
      a1 = *(const float4*)&A[(size_t)(row0 + am + 64) * D_DIM + k0 + 16 + ak];
      b0 = *(const float4*)&Bk[(size_t)(k0 + 16 + bk) * U_TAGS + bn];
      b1 = *(const float4*)&Bk[(size_t)(k0 + 16 + bk + 8) * U_TAGS + bn];
    }
#pragma unroll
    for (int kk = 0; kk < 16; ++kk) {
      float a[8], b[8];
      *(float4*)&a[0] = *(const float4*)&As[kk][ty * 8];
      *(float4*)&a[4] = *(const float4*)&As[kk][ty * 8 + 4];
      *(float4*)&b[0] = *(const float4*)&Bs[kk][tx * 4];
      *(float4*)&b[4] = *(const float4*)&Bs[kk][tx * 4 + 64];
#pragma unroll
      for (int r = 0; r < 8; ++r)
#pragma unroll
        for (int c = 0; c < 8; ++c) acc[r][c] = fmaf(a[r], b[c], acc[r][c]);
    }
    __syncthreads();
  }
#pragma unroll
  for (int r = 0; r < 8; ++r) {
    const int row = row0 + ty * 8 + r;
    const int t = row & (T_SEQ - 1);
    const int n0 = tx * 4, n1 = tx * 4 + 64;
    float o[8];
#pragma unroll
    for (int c = 0; c < 4; ++c) {
      float v = acc[r][c] + bias[n0 + c];
      if (t == 0) v += lb[n0 + c];
      if (t == T_SEQ - 1) v += rb[n0 + c];
      o[c] = v;
    }
#pragma unroll
    for (int c = 0; c < 4; ++c) {
      float v = acc[r][c + 4] + bias[n1 + c];
      if (t == 0) v += lb[n1 + c];
      if (t == T_SEQ - 1) v += rb[n1 + c];
      o[c + 4] = v;
    }
    *(float4*)&C[(size_t)row * U_TAGS + n0] = *(float4*)&o[0];
    *(float4*)&C[(size_t)row * U_TAGS + n1] = *(float4*)&o[4];
  }
}

// ---------------------------------------------------------------------------
// Viterbi helpers (unchanged, proven).
// ---------------------------------------------------------------------------
__device__ __forceinline__ float rl_f(float v, int lane) {
  return __int_as_float(__builtin_amdgcn_readlane(__float_as_int(v), lane));
}
template <int CTRL>
__device__ __forceinline__ float dpp_max_step(float x) {
  int v = __float_as_int(x);
  int t = __builtin_amdgcn_update_dpp(v, v, CTRL, 0xF, 0xF, false);
  return fmaxf(x, __int_as_float(t));
}
__device__ __forceinline__ float wave_max64_bcast(float x) {
  x = dpp_max_step<0x111>(x);  // row_shr:1
  x = dpp_max_step<0x112>(x);  // row_shr:2
  x = dpp_max_step<0x114>(x);  // row_shr:4
  x = dpp_max_step<0x118>(x);  // row_shr:8
  x = dpp_max_step<0x142>(x);  // row_bcast:15
  x = dpp_max_step<0x143>(x);  // row_bcast:31
  return rl_f(x, 63);
}
// keep a on ties; a must carry the smaller candidate index
__device__ __forceinline__ void win(float sa, int ia, float sb, int ib,
                                    float& so, int& io) {
  bool g = sa >= sb;
  so = g ? sa : sb;
  io = g ? ia : ib;
}

// ---------------------------------------------------------------------------
// Kernel 2 (split-K path): Viterbi with the combine FUSED into the producer
// wave. Producer reads p0,p1 partials and applies (p0+p1)+bias (+lb/rb) --
// identical add order to the old crf_combine -> bitwise-identical logits --
// while staging into the LDS ring. Consumer/backtrack byte-identical to the
// proven 586us kernel. Saves the 50MB combine pass + one dispatch.
// ---------------------------------------------------------------------------
__global__ __launch_bounds__(256) void crf_viterbi_fc(
    const float* __restrict__ ws,     // p0 at 0, p1 at M_ROWS*U_TAGS
    const float* __restrict__ bias, const float* __restrict__ lb,
    const float* __restrict__ rb,
    const float* __restrict__ trans,  // [128, 128]
    float* __restrict__ out) {        // [64, 512] fp32 tags
  __shared__ __align__(16) float trs[U_TAGS * U_TAGS];              // 64 KB
  __shared__ __align__(16) unsigned char bp[(T_SEQ - 1) * U_TAGS];  // 65408 B
  __shared__ __align__(16) float ring[4 * 8 * U_TAGS];              // 16 KB
  __shared__ int flags[2];  // [0]=chunks produced, [1]=chunks consumed
  __shared__ unsigned char tags[T_SEQ];
  __shared__ unsigned char M[8][U_TAGS];
  __shared__ unsigned char seedE[8];
  __shared__ float rmaxs[U_TAGS];
  __shared__ float wmin2[2];
  __shared__ float gminS;
  __shared__ int lastTagS;

  const int b = blockIdx.x;
  const int tid = threadIdx.x;

  // Stage trans (coalesced), 16 float4 per thread.
#pragma unroll
  for (int it = 0; it < 16; ++it)
    *(float4*)&trs[(it * 256 + tid) * 4] =
        *(const float4*)&trans[(it * 256 + tid) * 4];
  if (tid == 0) { flags[0] = 0; flags[1] = 0; }
  __syncthreads();

  // rmaxs[i] = max_j trs[i][j]; gmin = min over all trans.
  float rowmin = 1e30f;
  if (tid < U_TAGS) {
    float mx = -1e30f, mn = 1e30f;
    for (int q = 0; q < 32; ++q) {
      float4 v = *(const float4*)&trs[tid * U_TAGS + q * 4];
      mx = fmaxf(fmaxf(mx, v.x), fmaxf(v.y, fmaxf(v.z, v.w)));
      mn = fminf(fminf(mn, v.x), fminf(v.y, fminf(v.z, v.w)));
    }
    rmaxs[tid] = mx;
    rowmin = mn;
#pragma unroll
    for (int off = 1; off < 64; off <<= 1)
      rowmin = fminf(rowmin, __shfl_xor(rowmin, off));
    if ((tid & 63) == 0) wmin2[tid >> 6] = rowmin;
  }
  __syncthreads();
  if (tid == 0) gminS = fminf(wmin2[0], wmin2[1]);
  __syncthreads();

  const int wv = tid >> 6, l = tid & 63;
  volatile int* vfl = (volatile int*)flags;

  if (wv == 1) {
    // ---- producer with fused combine: 64 chunks x 8 steps x 128 tags ----
    const float4* p04 = (const float4*)ws + (size_t)b * 16384;
    const float4* p14 =
        (const float4*)(ws + (size_t)M_ROWS * U_TAGS) + (size_t)b * 16384;
    const float4 bias4 = ((const float4*)bias)[l & 31];
    const float4 lb4 = ((const float4*)lb)[l & 31];
    const float4 rb4 = ((const float4*)rb)[l & 31];
    float4* dst = (float4*)ring;
    for (int c = 0; c < 64; ++c) {
      while (vfl[1] + 4 <= c) { }  // ring credit
      const int i0 = c * 256 + l;  // float4 index within batch
      float4 v[4];
#pragma unroll
      for (int u = 0; u < 4; ++u) {
        const int f4g = i0 + u * 64;
        const float4 x0 = p04[f4g];
        const float4 x1 = p14[f4g];
        float4 o;
        o.x = x0.x + x1.x + bias4.x;
        o.y = x0.y + x1.y + bias4.y;
        o.z = x0.z + x1.z + bias4.z;
        o.w = x0.w + x1.w + bias4.w;
        if (f4g < 32) {  // t == 0
          o.x += lb4.x; o.y += lb4.y; o.z += lb4.z; o.w += lb4.w;
        }
        if (f4g >= 32 * (T_SEQ - 1)) {  // t == 511
          o.x += rb4.x; o.y += rb4.y; o.z += rb4.z; o.w += rb4.w;
        }
        v[u] = o;
      }
      float4* d4 = dst + (c & 3) * 256;
      d4[l] = v[0]; d4[l + 64] = v[1]; d4[l + 128] = v[2]; d4[l + 192] = v[3];
      __threadfence_block();
      if (l == 0) vfl[0] = c + 1;
    }
  } else if (wv == 0) {
    // ---- consumer: the whole forward recurrence, LDS-only (unchanged) ----
    const float cc0 = rmaxs[l] - gminS + 0.01f;
    const float cc1 = rmaxs[64 + l] - gminS + 0.01f;
    while (vfl[0] < 1) { }
    float v0 = ring[l];       // t=0 (lb fused)
    float v1 = ring[64 + l];
    const unsigned long long G = 0x8000000000000000ull;
    int bpoff = l;

    for (int t = 1; t < T_SEQ; ++t) {
      if ((t & 7) == 0) {
        const int c = t >> 3;
        if (l == 0) vfl[1] = c;       // chunks < c fully consumed
        while (vfl[0] <= c) { }
      }
      const float* sl = ring + ((t >> 3) & 3) * 1024 + (t & 7) * U_TAGS;
      float lg0 = sl[l];
      float lg1 = sl[64 + l];

      const float vm = wave_max64_bcast(fmaxf(v0, v1));
      unsigned long long m0 = __ballot(v0 + cc0 >= vm);
      unsigned long long m1 = __ballot(v1 + cc1 >= vm);

      // 3 slots per half; empty/dup -> guard index 63 (a real pair).
      unsigned long long rA1 = m0 & (m0 - 1), rA2 = rA1 & (rA1 - 1);
      unsigned long long rB1 = m1 & (m1 - 1), rB2 = rB1 & (rB1 - 1);
      const int iA0 = __builtin_ctzll(m0 | G);
      const int iA1 = __builtin_ctzll(rA1 | G);
      const int iA2 = __builtin_ctzll(rA2 | G);
      const int iB0 = __builtin_ctzll(m1 | G);
      const int iB1 = __builtin_ctzll(rB1 | G);
      const int iB2 = __builtin_ctzll(rB2 | G);
      unsigned long long tail = (rA2 & (rA2 - 1)) | (rB2 & (rB2 - 1));

      const float svA0 = rl_f(v0, iA0), svA1 = rl_f(v0, iA1),
                  svA2 = rl_f(v0, iA2);
      const float svB0 = rl_f(v1, iB0), svB1 = rl_f(v1, iB1),
                  svB2 = rl_f(v1, iB2);

      const float* pA0 = &trs[iA0 * U_TAGS + l];
      const float* pA1 = &trs[iA1 * U_TAGS + l];
      const float* pA2 = &trs[iA2 * U_TAGS + l];
      const float* pB0 = &trs[(64 + iB0) * U_TAGS + l];
      const float* pB1 = &trs[(64 + iB1) * U_TAGS + l];
      const float* pB2 = &trs[(64 + iB2) * U_TAGS + l];
      const float tA0L = pA0[0], tA0H = pA0[64];
      const float tA1L = pA1[0], tA1H = pA1[64];
      const float tA2L = pA2[0], tA2H = pA2[64];
      const float tB0L = pB0[0], tB0H = pB0[64];
      const float tB1L = pB1[0], tB1H = pB1[64];
      const float tB2L = pB2[0], tB2H = pB2[64];

      // L target (j = l)
      float wa, wb, wL; int xa, xb, xL;
      win(svA0 + tA0L, iA0, svA1 + tA1L, iA1, wa, xa);
      win(wa, xa, svA2 + tA2L, iA2, wa, xa);
      win(svB0 + tB0L, 64 + iB0, svB1 + tB1L, 64 + iB1, wb, xb);
      win(wb, xb, svB2 + tB2L, 64 + iB2, wb, xb);
      win(wa, xa, wb, xb, wL, xL);
      // H target (j = 64 + l)
      float wH; int xH;
      win(svA0 + tA0H, iA0, svA1 + tA1H, iA1, wa, xa);
      win(wa, xa, svA2 + tA2H, iA2, wa, xa);
      win(svB0 + tB0H, 64 + iB0, svB1 + tB1H, 64 + iB1, wb, xb);
      win(wb, xb, svB2 + tB2H, 64 + iB2, wb, xb);
      win(wa, xa, wb, xb, wH, xH);

      if (tail) {  // rare: >3 candidates in a half, tie-aware
        unsigned long long r = rA2 & (rA2 - 1);
        while (r) {
          int i = __builtin_ctzll(r); r &= r - 1;
          float vi = rl_f(v0, i);
          float sL = vi + trs[i * U_TAGS + l];
          float sH = vi + trs[i * U_TAGS + 64 + l];
          if (sL > wL || (sL == wL && i < xL)) { wL = sL; xL = i; }
          if (sH > wH || (sH == wH && i < xH)) { wH = sH; xH = i; }
        }
        r = rB2 & (rB2 - 1);
        while (r) {
          int i = __builtin_ctzll(r); r &= r - 1;
          float vi = rl_f(v1, i);
          float sL = vi + trs[(64 + i) * U_TAGS + l];
          float sH = vi + trs[(64 + i) * U_TAGS + 64 + l];
          if (sL > wL || (sL == wL && 64 + i < xL)) { wL = sL; xL = 64 + i; }
          if (sH > wH || (sH == wH && 64 + i < xH)) { wH = sH; xH = 64 + i; }
        }
      }

      bp[bpoff] = (unsigned char)xL;
      bp[bpoff + 64] = (unsigned char)xH;
      bpoff += U_TAGS;
      v0 = wL + lg0;  // same fp32 ops as reference
      v1 = wH + lg1;
    }

    // final argmax (first max over j=0..127)
    float val = v0; int idx = l;
    if (v1 > v0) { val = v1; idx = 64 + l; }
#pragma unroll
    for (int off = 1; off < 64; off <<= 1) {
      float vo = __shfl_xor(val, off);
      int io = __shfl_xor(idx, off);
      if (vo > val || (vo == val && io < idx)) { val = vo; idx = io; }
    }
    if (l == 0) { lastTagS = idx; tags[T_SEQ - 1] = (unsigned char)idx; }
  }
  __syncthreads();  // waves 2-3 waited here during the forward pass

  // Backtrack pass A: 1024 chains (8 chunks x 128 seeds), 4 per thread.
#pragma unroll
  for (int q = 0; q < 4; ++q) {
    const int chain = tid + q * 256;
    const int c = chain >> 7, s = chain & 127;
    const int lo = c * 64;
    const int hi = (c == 7) ? (T_SEQ - 2) : (c * 64 + 63);
    int cur = s;
    for (int t = hi; t >= lo; --t) cur = bp[t * U_TAGS + cur];
    M[c][s] = (unsigned char)cur;
  }
  __syncthreads();
  if (tid == 0) {
    int e = lastTagS;
    seedE[7] = (unsigned char)e;
    for (int c = 7; c >= 1; --c) { e = M[c][e]; seedE[c - 1] = (unsigned char)e; }
  }
  __syncthreads();
  if (tid < 8) {
    const int c = tid;
    const int lo = c * 64;
    const int hi = (c == 7) ? (T_SEQ - 2) : (c * 64 + 63);
    int cur = seedE[c];
    for (int t = hi; t >= lo; --t) {
      cur = bp[t * U_TAGS + cur];
      tags[t] = (unsigned char)cur;
    }
  }
  __syncthreads();
  out[(size_t)b * T_SEQ + tid] = (float)tags[tid];
  out[(size_t)b * T_SEQ + 256 + tid] = (float)tags[256 + tid];
}

// ---------------------------------------------------------------------------
// Fallback viterbi reading final logits (used only with fallback crf_gemm).
// ---------------------------------------------------------------------------
__global__ __launch_bounds__(256) void crf_viterbi(
    const float* __restrict__ logits, const float* __restrict__ trans,
    float* __restrict__ out) {
  __shared__ __align__(16) float trs[U_TAGS * U_TAGS];
  __shared__ __align__(16) unsigned char bp[(T_SEQ - 1) * U_TAGS];
  __shared__ __align__(16) float ring[4 * 8 * U_TAGS];
  __shared__ int flags[2];
  __shared__ unsigned char tags[T_SEQ];
  __shared__ unsigned char M[8][U_TAGS];
  __shared__ unsigned char seedE[8];
  __shared__ float rmaxs[U_TAGS];
  __shared__ float wmin2[2];
  __shared__ float gminS;
  __shared__ int lastTagS;

  const int b = blockIdx.x;
  const int tid = threadIdx.x;
  const float* lg_b = logits + (size_t)b * T_SEQ * U_TAGS;

#pragma unroll
  for (int it = 0; it < 16; ++it)
    *(float4*)&trs[(it * 256 + tid) * 4] =
        *(const float4*)&trans[(it * 256 + tid) * 4];
  if (tid == 0) { flags[0] = 0; flags[1] = 0; }
  __syncthreads();

  float rowmin = 1e30f;
  if (tid < U_TAGS) {
    float mx = -1e30f, mn = 1e30f;
    for (int q = 0; q < 32; ++q) {
      float4 v = *(const float4*)&trs[tid * U_TAGS + q * 4];
      mx = fmaxf(fmaxf(mx, v.x), fmaxf(v.y, fmaxf(v.z, v.w)));
      mn = fminf(fminf(mn, v.x), fminf(v.y, fminf(v.z, v.w)));
    }
    rmaxs[tid] = mx;
    rowmin = mn;
#pragma unroll
    for (int off = 1; off < 64; off <<= 1)
      rowmin = fminf(rowmin, __shfl_xor(rowmin, off));
    if ((tid & 63) == 0) wmin2[tid >> 6] = rowmin;
  }
  __syncthreads();
  if (tid == 0) gminS = fminf(wmin2[0], wmin2[1]);
  __syncthreads();

  const int wv = tid >> 6, l = tid & 63;
  volatile int* vfl = (volatile int*)flags;

  if (wv == 1) {
    const float4* src = (const float4*)lg_b;
    float4* dst = (float4*)ring;
    for (int c = 0; c < 64; ++c) {
      while (vfl[1] + 4 <= c) { }
      const float4* s4 = src + c * 256;
      float4 d0 = s4[l], d1 = s4[l + 64], d2 = s4[l + 128], d3 = s4[l + 192];
      float4* d4 = dst + (c & 3) * 256;
      d4[l] = d0; d4[l + 64] = d1; d4[l + 128] = d2; d4[l + 192] = d3;
      __threadfence_block();
      if (l == 0) vfl[0] = c + 1;
    }
  } else if (wv == 0) {
    const float cc0 = rmaxs[l] - gminS + 0.01f;
    const float cc1 = rmaxs[64 + l] - gminS + 0.01f;
    while (vfl[0] < 1) { }
    float v0 = ring[l];
    float v1 = ring[64 + l];
    const unsigned long long G = 0x8000000000000000ull;
    int bpoff = l;

    for (int t = 1; t < T_SEQ; ++t) {
      if ((t & 7) == 0) {
        const int c = t >> 3;
        if (l == 0) vfl[1] = c;
        while (vfl[0] <= c) { }
      }
      const float* sl = ring + ((t >> 3) & 3) * 1024 + (t & 7) * U_TAGS;
      float lg0 = sl[l];
      float lg1 = sl[64 + l];

      const float vm = wave_max64_bcast(fmaxf(v0, v1));
      unsigned long long m0 = __ballot(v0 + cc0 >= vm);
      unsigned long long m1 = __ballot(v1 + cc1 >= vm);

      unsigned long long rA1 = m0 & (m0 - 1), rA2 = rA1 & (rA1 - 1);
      unsigned long long rB1 = m1 & (m1 - 1), rB2 = rB1 & (rB1 - 1);
      const int iA0 = __builtin_ctzll(m0 | G);
      const int iA1 = __builtin_ctzll(rA1 | G);
      const int iA2 = __builtin_ctzll(rA2 | G);
      const int iB0 = __builtin_ctzll(m1 | G);
      const int iB1 = __builtin_ctzll(rB1 | G);
      const int iB2 = __builtin_ctzll(rB2 | G);
      unsigned long long tail = (rA2 & (rA2 - 1)) | (rB2 & (rB2 - 1));

      const float svA0 = rl_f(v0, iA0), svA1 = rl_f(v0, iA1),
                  svA2 = rl_f(v0, iA2);
      const float svB0 = rl_f(v1, iB0), svB1 = rl_f(v1, iB1),
                  svB2 = rl_f(v1, iB2);

      const float* pA0 = &trs[iA0 * U_TAGS + l];
      const float* pA1 = &trs[iA1 * U_TAGS + l];
      const float* pA2 = &trs[iA2 * U_TAGS + l];
      const float* pB0 = &trs[(64 + iB0) * U_TAGS + l];
      const float* pB1 = &trs[(64 + iB1) * U_TAGS + l];
      const float* pB2 = &trs[(64 + iB2) * U_TAGS + l];
      const float tA0L = pA0[0], tA0H = pA0[64];
      const float tA1L = pA1[0], tA1H = pA1[64];
      const float tA2L = pA2[0], tA2H = pA2[64];
      const float tB0L = pB0[0], tB0H = pB0[64];
      const float tB1L = pB1[0], tB1H = pB1[64];
      const float tB2L = pB2[0], tB2H = pB2[64];

      float wa, wb, wL; int xa, xb, xL;
      win(svA0 + tA0L, iA0, svA1 + tA1L, iA1, wa, xa);
      win(wa, xa, svA2 + tA2L, iA2, wa, xa);
      win(svB0 + tB0L, 64 + iB0, svB1 + tB1L, 64 + iB1, wb, xb);
      win(wb, xb, svB2 + tB2L, 64 + iB2, wb, xb);
      win(wa, xa, wb, xb, wL, xL);
      float wH; int xH;
      win(svA0 + tA0H, iA0, svA1 + tA1H, iA1, wa, xa);
      win(wa, xa, svA2 + tA2H, iA2, wa, xa);
      win(svB0 + tB0H, 64 + iB0, svB1 + tB1H, 64 + iB1, wb, xb);
      win(wb, xb, svB2 + tB2H, 64 + iB2, wb, xb);
      win(wa, xa, wb, xb, wH, xH);

      if (tail) {
        unsigned long long r = rA2 & (rA2 - 1);
        while (r) {
          int i = __builtin_ctzll(r); r &= r - 1;
          float vi = rl_f(v0, i);
          float sL = vi + trs[i * U_TAGS + l];
          float sH = vi + trs[i * U_TAGS + 64 + l];
          if (sL > wL || (sL == wL && i < xL)) { wL = sL; xL = i; }
          if (sH > wH || (sH == wH && i < xH)) { wH = sH; xH = i; }
        }
        r = rB2 & (rB2 - 1);
        while (r) {
          int i = __builtin_ctzll(r); r &= r - 1;
          float vi = rl_f(v1, i);
          float sL = vi + trs[(64 + i) * U_TAGS + l];
          float sH = vi + trs[(64 + i) * U_TAGS + 64 + l];
          if (sL > wL || (sL == wL && 64 + i < xL)) { wL = sL; xL = 64 + i; }
          if (sH > wH || (sH == wH && 64 + i < xH)) { wH = sH; xH = 64 + i; }
        }
      }

      bp[bpoff] = (unsigned char)xL;
      bp[bpoff + 64] = (unsigned char)xH;
      bpoff += U_TAGS;
      v0 = wL + lg0;
      v1 = wH + lg1;
    }

    float val = v0; int idx = l;
    if (v1 > v0) { val = v1; idx = 64 + l; }
#pragma unroll
    for (int off = 1; off < 64; off <<= 1) {
      float vo = __shfl_xor(val, off);
      int io = __shfl_xor(idx, off);
      if (vo > val || (vo == val && io < idx)) { val = vo; idx = io; }
    }
    if (l == 0) { lastTagS = idx; tags[T_SEQ - 1] = (unsigned char)idx; }
  }
  __syncthreads();

#pragma unroll
  for (int q = 0; q < 4; ++q) {
    const int chain = tid + q * 256;
    const int c = chain >> 7, s = chain & 127;
    const int lo = c * 64;
    const int hi = (c == 7) ? (T_SEQ - 2) : (c * 64 + 63);
    int cur = s;
    for (int t = hi; t >= lo; --t) cur = bp[t * U_TAGS + cur];
    M[c][s] = (unsigned char)cur;
  }
  __syncthreads();
  if (tid == 0) {
    int e = lastTagS;
    seedE[7] = (unsigned char)e;
    for (int c = 7; c >= 1; --c) { e = M[c][e]; seedE[c - 1] = (unsigned char)e; }
  }
  __syncthreads();
  if (tid < 8) {
    const int c = tid;
    const int lo = c * 64;
    const int hi = (c == 7) ? (T_SEQ - 2) : (c * 64 + 63);
    int cur = seedE[c];
    for (int t = hi; t >= lo; --t) {
      cur = bp[t * U_TAGS + cur];
      tags[t] = (unsigned char)cur;
    }
  }
  __syncthreads();
  out[(size_t)b * T_SEQ + tid] = (float)tags[tid];
  out[(size_t)b * T_SEQ + 256 + tid] = (float)tags[256 + tid];
}

// ---------------------------------------------------------------------------
extern "C" void kernel_launch(void* const* d_in, const int* in_sizes, int n_in,
                              void* d_out, int out_size, void* d_ws,
                              size_t ws_size, hipStream_t stream) {
  const float* x = (const float*)d_in[0];
  const float* kern = (const float*)d_in[1];
  const float* bias = (const float*)d_in[2];
  const float* chain = (const float*)d_in[3];
  const float* lb = (const float*)d_in[4];
  const float* rb = (const float*)d_in[5];
  float* out = (float*)d_out;

  const size_t part = (size_t)M_ROWS * U_TAGS * sizeof(float);  // 16.8 MB
  if (ws_size >= 2 * part) {
    crf_gemm_half<<<dim3(256, 2), 512, 0, stream>>>(x, kern, (float*)d_ws);
    crf_viterbi_fc<<<64, 256, 0, stream>>>((const float*)d_ws, bias, lb, rb,
                                           chain, out);
  } else {
    float* logits = (float*)d_ws;
    crf_gemm<<<256, 256, 0, stream>>>(x, kern, bias, lb, rb, logits);
    crf_viterbi<<<64, 256, 0, stream>>>(logits, chain, out);
  }
}